// Round 2
// baseline (1044.358 us; speedup 1.0000x reference)
//
#include <hip/hip_runtime.h>

// Problem constants (fixed by setup_inputs)
#define BB 32
#define CC 3
#define HH 257
#define WW 257
#define MASK 17
#define STRIDE 4
#define NWIN 61           // (257-17)/4+1

constexpr int WIN_ELEMS = MASK * MASK;               // 289
constexpr int ROW_ELEMS = NWIN * WIN_ELEMS;          // 17629 contiguous sw elems per (b,c,i)
constexpr int LDS_ELEMS = MASK * WW;                 // 4369 floats (17 contiguous input rows)
constexpr long long SW_SIZE = (long long)BB * CC * NWIN * NWIN * WIN_ELEMS; // 103,235,424
constexpr long long S_SIZE  = (long long)BB * 4 * CC * NWIN * NWIN;         // 1,428,864
constexpr int NN2 = NWIN * NWIN;                     // 3721

__global__ __launch_bounds__(256) void leafnet_kernel(
        const float* __restrict__ x,
        float* __restrict__ sw_out,
        float* __restrict__ s_out,
        float* __restrict__ q_out) {
    __shared__ float lds[LDS_ELEMS];

    const int bid = blockIdx.x;           // (b, c, i)
    const int i = bid % NWIN;
    const int c = (bid / NWIN) % CC;
    const int b = bid / (NWIN * CC);
    const int tid = threadIdx.x;

    // Stage 17 consecutive full rows (contiguous in memory) into LDS.
    const float* xbase = x + ((size_t)(b * CC + c) * HH + (size_t)i * STRIDE) * WW;
    for (int e = tid; e < LDS_ELEMS; e += 256) {
        lds[e] = xbase[e];
    }
    __syncthreads();

    // ---- sw + q: one contiguous span of 17629 elems each, coalesced stores ----
    const size_t obase = (size_t)bid * ROW_ELEMS;
    for (int o = tid; o < ROW_ELEMS; o += 256) {
        int j = o / WIN_ELEMS;            // const-div -> magic mul
        int r = o - j * WIN_ELEMS;
        int u = r / MASK;
        int v = r - u * MASK;
        float xv = lds[u * WW + j * STRIDE + v];
        // digitize(x, linspace(0,1,65)) - 1 == clamp(floor(64*x), -1, 64)
        // (x*64 is an exact pow2 multiply; edges k/64 are exact fp32)
        int qi = (int)floorf(xv * 64.0f);
        qi = qi < -1 ? -1 : (qi > 64 ? 64 : qi);
        __builtin_nontemporal_store(xv, sw_out + obase + o);
        __builtin_nontemporal_store((float)qi, q_out + obase + o);
    }

    // ---- stats: one wave per window, 61 windows round-robin over 4 waves ----
    const int wave = tid >> 6;
    const int lane = tid & 63;
    for (int j = wave; j < NWIN; j += 4) {
        float sum = 0.0f, sumsq = 0.0f, mx = -1e30f, mn = 1e30f;
        for (int e = lane; e < WIN_ELEMS; e += 64) {
            int u = e / MASK;
            int v = e - u * MASK;
            float xv = lds[u * WW + j * STRIDE + v];
            sum += xv;
            sumsq += xv * xv;
            mx = fmaxf(mx, xv);
            mn = fminf(mn, xv);
        }
        #pragma unroll
        for (int off = 32; off > 0; off >>= 1) {
            sum   += __shfl_xor(sum, off, 64);
            sumsq += __shfl_xor(sumsq, off, 64);
            mx = fmaxf(mx, __shfl_xor(mx, off, 64));
            mn = fminf(mn, __shfl_xor(mn, off, 64));
        }
        if (lane == 0) {
            const float inv_n = 1.0f / (float)WIN_ELEMS;
            float mean = sum * inv_n;
            float var = fmaxf(sumsq * inv_n - mean * mean, 0.0f); // population std
            float sd = sqrtf(var);
            const float inv_std = 4.0f;  // 1 / G_STD
            // s[b, g*3 + c, i, j], s shape (B, 12, 61, 61)
            size_t sb = (size_t)b * 12 * NN2 + (size_t)c * NN2 + (size_t)i * NWIN + j;
            s_out[sb + 0 * (size_t)CC * NN2] = (mx - 0.5f) * inv_std;
            s_out[sb + 1 * (size_t)CC * NN2] = sd * inv_std;
            s_out[sb + 2 * (size_t)CC * NN2] = (mx - mean) * inv_std;
            s_out[sb + 3 * (size_t)CC * NN2] = (mean - mn) * inv_std;
        }
    }
}

extern "C" void kernel_launch(void* const* d_in, const int* in_sizes, int n_in,
                              void* d_out, int out_size, void* d_ws, size_t ws_size,
                              hipStream_t stream) {
    const float* x = (const float*)d_in[0];
    // d_in[1] = bins (linspace(0,1,65)) — semantics hardcoded (exact, see kernel)
    float* out = (float*)d_out;
    float* sw_out = out;
    float* s_out  = out + SW_SIZE;
    float* q_out  = out + SW_SIZE + S_SIZE;

    const int grid = BB * CC * NWIN;   // 5856 blocks, one per (b,c,i)
    leafnet_kernel<<<grid, 256, 0, stream>>>(x, sw_out, s_out, q_out);
}

// Round 3
// 977.051 us; speedup vs baseline: 1.0689x; 1.0689x over previous
//
#include <hip/hip_runtime.h>

// Problem constants (fixed by setup_inputs)
#define BB 32
#define CC 3
#define HH 257
#define WW 257
#define MASK 17
#define STRIDE 4
#define NWIN 61           // (257-17)/4+1

constexpr int WIN_ELEMS = MASK * MASK;               // 289
constexpr int ROW_ELEMS = NWIN * WIN_ELEMS;          // 17629 contiguous sw elems per (b,c,i)
constexpr int LDS_ELEMS = MASK * WW;                 // 4369 floats (17 contiguous input rows)
constexpr long long SW_SIZE = (long long)BB * CC * NWIN * NWIN * WIN_ELEMS; // 103,235,424
constexpr long long S_SIZE  = (long long)BB * 4 * CC * NWIN * NWIN;         // 1,428,864
constexpr int NN2 = NWIN * NWIN;                     // 3721

static __device__ __forceinline__ void compute_elem(
        const float* __restrict__ lds, int o, float& sv, float& qv) {
    int j = o / WIN_ELEMS;            // const-div -> magic mul
    int r = o - j * WIN_ELEMS;
    int u = r / MASK;
    int v = r - u * MASK;
    float xv = lds[u * WW + j * STRIDE + v];
    // digitize(x, linspace(0,1,65)) - 1 == clamp(floor(64*x), -1, 64)
    // (x*64 is an exact pow2 multiply; edges k/64 are exact fp32)
    int qi = (int)floorf(xv * 64.0f);
    qi = qi < -1 ? -1 : (qi > 64 ? 64 : qi);
    sv = xv;
    qv = (float)qi;
}

__global__ __launch_bounds__(256) void leafnet_kernel(
        const float* __restrict__ x,
        float* __restrict__ sw_out,
        float* __restrict__ s_out,
        float* __restrict__ q_out) {
    __shared__ float lds[LDS_ELEMS];

    const int bid = blockIdx.x;           // (b, c, i)
    const int i = bid % NWIN;
    const int c = (bid / NWIN) % CC;
    const int b = bid / (NWIN * CC);
    const int tid = threadIdx.x;

    // Stage 17 consecutive full rows (contiguous in memory) into LDS.
    const float* xbase = x + ((size_t)(b * CC + c) * HH + (size_t)i * STRIDE) * WW;
    for (int e = tid; e < LDS_ELEMS; e += 256) {
        lds[e] = xbase[e];
    }
    __syncthreads();

    // ---- sw + q: contiguous span [obase, obase+17629) per block ----
    // Span length is odd -> explicit head/body/tail for 16B-aligned float4 stores.
    // Both sw_out and q_out bases are 16B-aligned (offsets 0 and 104,664,288 elems).
    const size_t obase = (size_t)bid * ROW_ELEMS;
    const size_t gend  = obase + ROW_ELEMS;
    const size_t g0    = (obase + 3) & ~(size_t)3;   // first aligned element
    const size_t gbe   = gend & ~(size_t)3;          // end of aligned body
    const int head  = (int)(g0 - obase);             // 0..3
    const int tailn = (int)(gend - gbe);             // 0..3
    const int body  = (int)((gbe - g0) >> 2);        // float4 chunks (~4407)

    // scalar head + tail (<= 6 elements total)
    if (tid < 8) {
        int o = -1;
        if (tid < head) o = tid;
        else if (tid - head < tailn) o = (int)(gbe - obase) + (tid - head);
        if (o >= 0) {
            float sv, qv;
            compute_elem(lds, o, sv, qv);
            sw_out[obase + o] = sv;
            q_out[obase + o] = qv;
        }
    }

    // vectorized body: one float4 per thread per iteration, plain (cached) stores
    for (int k = tid; k < body; k += 256) {
        size_t g = g0 + ((size_t)k << 2);
        int o = (int)(g - obase);
        float s0, s1, s2, s3, q0, q1, q2, q3;
        compute_elem(lds, o + 0, s0, q0);
        compute_elem(lds, o + 1, s1, q1);
        compute_elem(lds, o + 2, s2, q2);
        compute_elem(lds, o + 3, s3, q3);
        *reinterpret_cast<float4*>(sw_out + g) = make_float4(s0, s1, s2, s3);
        *reinterpret_cast<float4*>(q_out + g)  = make_float4(q0, q1, q2, q3);
    }

    // ---- stats: one wave per window, 61 windows round-robin over 4 waves ----
    const int wave = tid >> 6;
    const int lane = tid & 63;
    for (int j = wave; j < NWIN; j += 4) {
        float sum = 0.0f, sumsq = 0.0f, mx = -1e30f, mn = 1e30f;
        for (int e = lane; e < WIN_ELEMS; e += 64) {
            int u = e / MASK;
            int v = e - u * MASK;
            float xv = lds[u * WW + j * STRIDE + v];
            sum += xv;
            sumsq += xv * xv;
            mx = fmaxf(mx, xv);
            mn = fminf(mn, xv);
        }
        #pragma unroll
        for (int off = 32; off > 0; off >>= 1) {
            sum   += __shfl_xor(sum, off, 64);
            sumsq += __shfl_xor(sumsq, off, 64);
            mx = fmaxf(mx, __shfl_xor(mx, off, 64));
            mn = fminf(mn, __shfl_xor(mn, off, 64));
        }
        if (lane == 0) {
            const float inv_n = 1.0f / (float)WIN_ELEMS;
            float mean = sum * inv_n;
            float var = fmaxf(sumsq * inv_n - mean * mean, 0.0f); // population std
            float sd = sqrtf(var);
            const float inv_std = 4.0f;  // 1 / G_STD
            // s[b, g*3 + c, i, j], s shape (B, 12, 61, 61)
            size_t sb = (size_t)b * 12 * NN2 + (size_t)c * NN2 + (size_t)i * NWIN + j;
            s_out[sb + 0 * (size_t)CC * NN2] = (mx - 0.5f) * inv_std;
            s_out[sb + 1 * (size_t)CC * NN2] = sd * inv_std;
            s_out[sb + 2 * (size_t)CC * NN2] = (mx - mean) * inv_std;
            s_out[sb + 3 * (size_t)CC * NN2] = (mean - mn) * inv_std;
        }
    }
}

extern "C" void kernel_launch(void* const* d_in, const int* in_sizes, int n_in,
                              void* d_out, int out_size, void* d_ws, size_t ws_size,
                              hipStream_t stream) {
    const float* x = (const float*)d_in[0];
    // d_in[1] = bins (linspace(0,1,65)) — semantics hardcoded (exact, see kernel)
    float* out = (float*)d_out;
    float* sw_out = out;
    float* s_out  = out + SW_SIZE;
    float* q_out  = out + SW_SIZE + S_SIZE;

    const int grid = BB * CC * NWIN;   // 5856 blocks, one per (b,c,i)
    leafnet_kernel<<<grid, 256, 0, stream>>>(x, sw_out, s_out, q_out);
}

// Round 4
// 950.594 us; speedup vs baseline: 1.0986x; 1.0278x over previous
//
#include <hip/hip_runtime.h>

// Problem constants (fixed by setup_inputs)
#define BB 32
#define CC 3
#define HH 257
#define WW 257
#define MASK 17
#define STRIDE 4
#define NWIN 61           // (257-17)/4+1

constexpr int WIN_ELEMS = MASK * MASK;               // 289
constexpr int ROW_ELEMS = NWIN * WIN_ELEMS;          // 17629 contiguous sw elems per (b,c,i)
constexpr int LDSP = 260;                            // padded LDS row pitch (260 mod 32 = 4 -> banks spread)
constexpr long long SW_SIZE = (long long)BB * CC * NWIN * NWIN * WIN_ELEMS; // 103,235,424
constexpr long long S_SIZE  = (long long)BB * 4 * CC * NWIN * NWIN;         // 1,428,864
constexpr int NN2 = NWIN * NWIN;                     // 3721

static __device__ __forceinline__ void compute_elem(
        const float* __restrict__ lds, int o, float& sv, float& qv) {
    int j = o / WIN_ELEMS;            // const-div -> magic mul
    int r = o - j * WIN_ELEMS;
    int u = r / MASK;
    int v = r - u * MASK;
    float xv = lds[u * LDSP + j * STRIDE + v];
    // digitize(x, linspace(0,1,65)) - 1 == clamp(floor(64*x), -1, 64)
    // (x*64 is an exact pow2 multiply; edges k/64 are exact fp32)
    int qi = (int)floorf(xv * 64.0f);
    qi = qi < -1 ? -1 : (qi > 64 ? 64 : qi);
    sv = xv;
    qv = (float)qi;
}

__global__ __launch_bounds__(256) void leafnet_kernel(
        const float* __restrict__ x,
        float* __restrict__ sw_out,
        float* __restrict__ s_out,
        float* __restrict__ q_out) {
    __shared__ float lds[MASK * LDSP];   // 17 x 260 floats = 17.68 KB

    const int bid = blockIdx.x;           // (b, c, i)
    const int i = bid % NWIN;
    const int c = (bid / NWIN) % CC;
    const int b = bid / (NWIN * CC);
    const int tid = threadIdx.x;

    // Stage 17 consecutive full rows into LDS with padded pitch.
    const float* xbase = x + ((size_t)(b * CC + c) * HH + (size_t)i * STRIDE) * WW;
    for (int e = tid; e < MASK * WW; e += 256) {
        int u = e / WW;                   // magic div by 257
        int w = e - u * WW;
        lds[u * LDSP + w] = xbase[e];
    }
    __syncthreads();

    // ---- sw + q: contiguous span [obase, obase+17629) per block ----
    const size_t obase = (size_t)bid * ROW_ELEMS;
    const size_t gend  = obase + ROW_ELEMS;
    const size_t g0    = (obase + 3) & ~(size_t)3;   // first 16B-aligned element
    const size_t gbe   = gend & ~(size_t)3;          // end of aligned body
    const int head  = (int)(g0 - obase);             // 0..3
    const int tailn = (int)(gend - gbe);             // 0..3
    const int body  = (int)((gbe - g0) >> 2);        // float4 chunks (~4407)

    // scalar head + tail (<= 6 elements total)
    if (tid < 8) {
        int o = -1;
        if (tid < head) o = tid;
        else if (tid - head < tailn) o = (int)(gbe - obase) + (tid - head);
        if (o >= 0) {
            float sv, qv;
            compute_elem(lds, o, sv, qv);
            sw_out[obase + o] = sv;
            q_out[obase + o] = qv;
        }
    }

    // vectorized body: one float4 per thread per iteration
    for (int k = tid; k < body; k += 256) {
        size_t g = g0 + ((size_t)k << 2);
        int o = (int)(g - obase);
        float s0, s1, s2, s3, q0, q1, q2, q3;
        compute_elem(lds, o + 0, s0, q0);
        compute_elem(lds, o + 1, s1, q1);
        compute_elem(lds, o + 2, s2, q2);
        compute_elem(lds, o + 3, s3, q3);
        *reinterpret_cast<float4*>(sw_out + g) = make_float4(s0, s1, s2, s3);
        *reinterpret_cast<float4*>(q_out + g)  = make_float4(q0, q1, q2, q3);
    }

    // ---- stats: quad-of-lanes per window ----
    // lane layout: j = (lane>>2) + 16*wave, q = lane&3 -> quarter of the 289 elems.
    const int lane = tid & 63;
    const int wave = tid >> 6;
    const int j = (lane >> 2) + (wave << 4);   // 0..63; valid if < 61
    const int q = lane & 3;

    float sum = 0.0f, sumsq = 0.0f, mx = -1e30f, mn = 1e30f;
    if (j < NWIN) {
        const int e0 = 72 * q;
        const int lim = (q == 3) ? 73 : 72;    // 289 = 72*4 + 1
        const int jbase = j * STRIDE;
        for (int s = 0; s < lim; ++s) {
            int e = e0 + s;
            int u = e / MASK;                  // const-div
            int v = e - u * MASK;
            float xv = lds[u * LDSP + jbase + v];
            sum += xv;
            sumsq += xv * xv;
            mx = fmaxf(mx, xv);
            mn = fminf(mn, xv);
        }
    }
    // combine the 4 quarter-partials (lanes 4g..4g+3 share one window)
    sum   += __shfl_xor(sum, 1, 64);
    sumsq += __shfl_xor(sumsq, 1, 64);
    mx = fmaxf(mx, __shfl_xor(mx, 1, 64));
    mn = fminf(mn, __shfl_xor(mn, 1, 64));
    sum   += __shfl_xor(sum, 2, 64);
    sumsq += __shfl_xor(sumsq, 2, 64);
    mx = fmaxf(mx, __shfl_xor(mx, 2, 64));
    mn = fminf(mn, __shfl_xor(mn, 2, 64));

    if (q == 0 && j < NWIN) {
        const float inv_n = 1.0f / (float)WIN_ELEMS;
        float mean = sum * inv_n;
        float var = fmaxf(sumsq * inv_n - mean * mean, 0.0f); // population std
        float sd = sqrtf(var);
        const float inv_std = 4.0f;  // 1 / G_STD
        // s[b, g*3 + c, i, j], s shape (B, 12, 61, 61)
        size_t sb = (size_t)b * 12 * NN2 + (size_t)c * NN2 + (size_t)i * NWIN + j;
        s_out[sb + 0 * (size_t)CC * NN2] = (mx - 0.5f) * inv_std;
        s_out[sb + 1 * (size_t)CC * NN2] = sd * inv_std;
        s_out[sb + 2 * (size_t)CC * NN2] = (mx - mean) * inv_std;
        s_out[sb + 3 * (size_t)CC * NN2] = (mean - mn) * inv_std;
    }
}

extern "C" void kernel_launch(void* const* d_in, const int* in_sizes, int n_in,
                              void* d_out, int out_size, void* d_ws, size_t ws_size,
                              hipStream_t stream) {
    const float* x = (const float*)d_in[0];
    // d_in[1] = bins (linspace(0,1,65)) — semantics hardcoded (exact, see kernel)
    float* out = (float*)d_out;
    float* sw_out = out;
    float* s_out  = out + SW_SIZE;
    float* q_out  = out + SW_SIZE + S_SIZE;

    const int grid = BB * CC * NWIN;   // 5856 blocks, one per (b,c,i)
    leafnet_kernel<<<grid, 256, 0, stream>>>(x, sw_out, s_out, q_out);
}